// Round 3
// baseline (171.158 us; speedup 1.0000x reference)
//
#include <hip/hip_runtime.h>
#include <math.h>

// CRF loss: B=256, L=256, T=50. One block (256 thr = 4 waves) per batch element.
// lane = "to" tag (>=50 pad); wave g covers from-rows [16g, 16g+15].
// Log2-domain scan, renormalized: stored A = alpha - S, S += c (c = exact max of prev A).
//
// Round-3 change: phase B is redundant across waves, so every wave holds all 64
// A-values in its own lanes -> stage the from-group via v_readlane (SALU) instead
// of an LDS write/waitcnt/read round trip. One barrier per step remains (the
// cross-wave partial exchange), parity-double-buffered.

#define TAGS 50
#define LEN 256
#define INV_LN2 1.4426950408889634f
#define LN2 0.6931471805599453f

#if __has_builtin(__builtin_amdgcn_exp2f)
#define EXP2F(x) __builtin_amdgcn_exp2f(x)
#else
#define EXP2F(x) exp2f(x)
#endif
#if __has_builtin(__builtin_amdgcn_logf)
#define LOG2F(x) __builtin_amdgcn_logf(x)
#else
#define LOG2F(x) log2f(x)
#endif

__device__ __forceinline__ float readlane_f(float v, int srclane) {
  return __builtin_bit_cast(float,
      __builtin_amdgcn_readlane(__builtin_bit_cast(int, v), srclane));
}

__global__ __launch_bounds__(256) void crf_fwd_kernel(
    const float* __restrict__ feats,   // (B, L, T)
    const float* __restrict__ trans,   // (T, T)
    const int*   __restrict__ tags,    // (B, L)
    const int*   __restrict__ mask,    // (B, L)
    float*       __restrict__ out)     // (B,)
{
  const int b    = blockIdx.x;
  const int t    = threadIdx.x;
  const int g    = t >> 6;                                  // wave id 0..3
  const int gu   = __builtin_amdgcn_readfirstlane(g);       // wave-uniform SGPR
  const int lane = t & 63;                                  // "to" tag (>=50 pad)
  const int toc  = lane < TAGS ? lane : (TAGS - 1);
  const int base = gu * 16;                                 // from-rows [base, base+15]

  __shared__ __align__(16) float feats_lds[LEN * TAGS];     // emits, prescaled by 1/ln2
  __shared__ int   mask_lds[LEN];
  __shared__ float partialDB[2][4][64];                     // parity-double-buffered
  __shared__ __align__(16) float maxDB[2][4];
  __shared__ float red[8];

  const float* fb = feats + (size_t)b * (LEN * TAGS);
  const int*   tb = tags + b * LEN;
  const int*   mb = mask + b * LEN;

  // ---- Bulk preload: feats[b] (12800 floats, prescaled) + mask[b] ----
  {
    const float4* fv = (const float4*)fb;                   // 3200 float4
    for (int i = t; i < (LEN * TAGS) / 4; i += 256) {
      float4 v = fv[i];
      v.x *= INV_LN2; v.y *= INV_LN2; v.z *= INV_LN2; v.w *= INV_LN2;
      *(float4*)&feats_lds[i * 4] = v;
    }
    mask_lds[t] = mb[t];
  }

  // Trans column slice for this wave's 16 from-rows (log2-scaled).
  float t2col[16];
#pragma unroll
  for (int f = 0; f < 16; ++f) {
    int row = base + f;
    if (row > TAGS - 1) row = TAGS - 1;  // dead rows (alpha=-inf) -> value irrelevant
    t2col[f] = trans[row * TAGS + toc] * INV_LN2;
  }

  __syncthreads();

  float A = (lane < TAGS) ? feats_lds[lane] : -INFINITY;    // stored log2-alpha
  float S = 0.0f;

  // Prefetch emit/mask for step 1 (LDS, latency overlapped with first readlanes).
  float e_nxt = feats_lds[1 * TAGS + toc];
  int   m_nxt = mask_lds[1];

  for (int l = 1; l < LEN; ++l) {
    const int par = l & 1;
    const float e_cur = e_nxt;
    const int   m_cur = m_nxt;
    const int   lnext = (l + 1 < LEN) ? (l + 1) : (LEN - 1);
    e_nxt = feats_lds[lnext * TAGS + toc];
    m_nxt = mask_lds[lnext];

    // ---- Stage from-group via readlane (every wave holds all A in its lanes) ----
    float av[16];
#pragma unroll
    for (int f = 0; f < 16; ++f) av[f] = readlane_f(A, base + f);

    // ---- Phase A: partial logsumexp over this wave's 16 from-rows ----
    float loc = av[0];
    float s0 = 0.0f, s1 = 0.0f;
#pragma unroll
    for (int f = 0; f < 16; ++f) {
      if (f) loc = fmaxf(loc, av[f]);
      const float v = EXP2F(av[f] + t2col[f]);              // exp2(-inf + x) = 0 for pads
      if (f & 1) s1 += v; else s0 += v;
    }
    partialDB[par][g][lane] = s0 + s1;
    if (lane == 0) maxDB[par][g] = loc;
    __syncthreads();                                         // the ONE barrier per step

    // ---- Phase B: finalize (all waves redundantly; alpha stays in registers) ----
    const float p = partialDB[par][0][lane] + partialDB[par][1][lane]
                  + partialDB[par][2][lane] + partialDB[par][3][lane];
    const float4 mx = *(const float4*)&maxDB[par][0];
    const float c = fmaxf(fmaxf(mx.x, mx.y), fmaxf(mx.z, mx.w)); // exact max of prev A
    float newA = LOG2F(p) + e_cur - c;
    newA = (m_cur > 0) ? newA : (A - c);                     // masked: alpha unchanged (abs)
    if (lane >= TAGS) newA = -INFINITY;                      // keep pads dead
    A = newA;
    S += c;
  }

  // ---- Gold score: thread t handles sequence position l = t ----
  const int tg = tb[t];
  const int mm = mask_lds[t];
  float gp = 0.0f;
  if (mm > 0) {
    gp = feats_lds[t * TAGS + tg] * LN2;                     // un-prescale
    if (t >= 1) gp += trans[tb[t - 1] * TAGS + tg];
  }
#pragma unroll
  for (int off = 32; off; off >>= 1) gp += __shfl_xor(gp, off, 64);
  if (lane == 0) red[g] = gp;
  __syncthreads();
  if (t == 0) red[4] = red[0] + red[1] + red[2] + red[3];
  __syncthreads();

  // ---- Final logsumexp over A (wave 0; pads are -inf) ----
  if (g == 0) {
    float m = A;
#pragma unroll
    for (int off = 32; off; off >>= 1) m = fmaxf(m, __shfl_xor(m, off, 64));
    float sum = EXP2F(A - m);
#pragma unroll
    for (int off = 32; off; off >>= 1) sum += __shfl_xor(sum, off, 64);
    if (lane == 0) {
      const float all_path = LN2 * (S + m + LOG2F(sum));
      out[b] = all_path - red[4];
    }
  }
}

extern "C" void kernel_launch(void* const* d_in, const int* in_sizes, int n_in,
                              void* d_out, int out_size, void* d_ws, size_t ws_size,
                              hipStream_t stream) {
  const float* feats = (const float*)d_in[0];
  const float* trans = (const float*)d_in[1];
  const int*   tags  = (const int*)d_in[2];
  const int*   mask  = (const int*)d_in[3];
  float* out = (float*)d_out;

  const int B = out_size;  // 256
  crf_fwd_kernel<<<B, 256, 0, stream>>>(feats, trans, tags, mask, out);
}

// Round 5
// 119.799 us; speedup vs baseline: 1.4287x; 1.4287x over previous
//
#include <hip/hip_runtime.h>
#include <math.h>

// CRF loss: B=256, L=256, T=50. ONE WAVE (64 threads) per batch element,
// barrier-free scan. lane = "to" tag (>=50 pad).
//
// Key algebraic change (R4): factor the exp —
//   exp2(A[f] + t2[f][to]) = exp2(A[f]) * E2[f][to],  E2 = exp2(trans/ln2) CONSTANT.
// Per step: w = exp2(A) (ONE exp2 per lane), then a 50-term dot product
// (readlane + fma, full-rate VALU). Renorm by c = newA[0] (invariant A[0]=0),
// which bounds |A| <= ~31 log2-units: exp2/fp32 safe, acc > 0 guaranteed.
//   stored A = alpha/ln2 - S;  S += c each step;  alpha recoverable as ln2*(A+S).

#define TAGS 50
#define LEN 256
#define INV_LN2 1.4426950408889634f
#define LN2 0.6931471805599453f

#if __has_builtin(__builtin_amdgcn_exp2f)
#define EXP2F(x) __builtin_amdgcn_exp2f(x)
#else
#define EXP2F(x) exp2f(x)
#endif
#if __has_builtin(__builtin_amdgcn_logf)
#define LOG2F(x) __builtin_amdgcn_logf(x)
#else
#define LOG2F(x) log2f(x)
#endif

__device__ __forceinline__ float readlane_f(float v, int srclane) {
  return __builtin_bit_cast(float,
      __builtin_amdgcn_readlane(__builtin_bit_cast(int, v), srclane));
}

__global__ __launch_bounds__(64) void crf_fwd_kernel(
    const float* __restrict__ feats,   // (B, L, T)
    const float* __restrict__ trans,   // (T, T)
    const int*   __restrict__ tags,    // (B, L)
    const int*   __restrict__ mask,    // (B, L)
    float*       __restrict__ out)     // (B,)
{
  const int b    = blockIdx.x;
  const int lane = threadIdx.x;                       // "to" tag (>=50 pad)
  const int toc  = lane < TAGS ? lane : (TAGS - 1);

  __shared__ __align__(16) float feats_lds[LEN * TAGS]; // emits, prescaled by 1/ln2
  __shared__ int mask_lds[LEN];

  const float* fb = feats + (size_t)b * (LEN * TAGS);
  const int*   tb = tags + b * LEN;
  const int*   mb = mask + b * LEN;

  // ---- Bulk preload: feats[b] (prescaled) + mask[b] ----
  {
    const float4* fv = (const float4*)fb;             // 3200 float4
    for (int i = lane; i < (LEN * TAGS) / 4; i += 64) {
      float4 v = fv[i];
      v.x *= INV_LN2; v.y *= INV_LN2; v.z *= INV_LN2; v.w *= INV_LN2;
      *(float4*)&feats_lds[i * 4] = v;
    }
    for (int i = lane; i < LEN; i += 64) mask_lds[i] = mb[i];
  }

  // Tags for gold score into registers (latency overlapped with preload).
  int tg_c[4], tg_p[4];
#pragma unroll
  for (int k = 0; k < 4; ++k) {
    const int p = lane + 64 * k;
    tg_c[k] = tb[p];
    tg_p[k] = (p >= 1) ? tb[p - 1] : 0;
  }

  // Constant exp-domain trans column for this lane: E2[f] = exp2(trans[f][toc]/ln2).
  float E2[TAGS];
#pragma unroll
  for (int f = 0; f < TAGS; ++f)
    E2[f] = EXP2F(trans[f * TAGS + toc] * INV_LN2);

  __syncthreads();                                    // single wave: just a waitcnt

  // Init: A = emit0/ln2, renormalized so A[0] == 0.
  float A = feats_lds[toc];
  float S;
  {
    const float c0 = readlane_f(A, 0);
    A -= c0;
    S = c0;
  }

  float e_nxt = feats_lds[TAGS + toc];
  int   m_nxt = mask_lds[1];

  for (int l = 1; l < LEN; ++l) {
    const float e_cur = e_nxt;
    const int   m_cur = m_nxt;
    const int   ln = (l + 1 < LEN) ? (l + 1) : (LEN - 1);
    e_nxt = feats_lds[ln * TAGS + toc];
    m_nxt = mask_lds[ln];

    const float w = EXP2F(A);                         // ONE exp2 per lane per step
    float acc[4] = {0.0f, 0.0f, 0.0f, 0.0f};
#pragma unroll
    for (int f = 0; f < TAGS; ++f) {
      const float wf = readlane_f(w, f);              // broadcast via SGPR
      acc[f & 3] = fmaf(wf, E2[f], acc[f & 3]);
    }
    const float p = (acc[0] + acc[1]) + (acc[2] + acc[3]);  // > 0: w[0]==1 -> p >= E2[0]
    const float raw = LOG2F(p) + e_cur;
    const float newA = (m_cur > 0) ? raw : A;         // masked: alpha unchanged
    const float c = readlane_f(newA, 0);              // cheap renorm (not max)
    A = newA - c;                                     // invariant: A[0] == 0
    S += c;
  }

  if (lane >= TAGS) A = -INFINITY;                    // kill pads for final LSE

  // ---- Final logsumexp over A ----
  float mx = A;
#pragma unroll
  for (int off = 32; off; off >>= 1) mx = fmaxf(mx, __shfl_xor(mx, off, 64));
  float sum = EXP2F(A - mx);
#pragma unroll
  for (int off = 32; off; off >>= 1) sum += __shfl_xor(sum, off, 64);

  // ---- Gold score: lane handles positions lane, lane+64, lane+128, lane+192 ----
  float gp = 0.0f;
#pragma unroll
  for (int k = 0; k < 4; ++k) {
    const int p = lane + 64 * k;
    if (mask_lds[p] > 0) {
      float v = feats_lds[p * TAGS + tg_c[k]] * LN2;  // un-prescale
      if (p >= 1) v += trans[tg_p[k] * TAGS + tg_c[k]];
      gp += v;
    }
  }
#pragma unroll
  for (int off = 32; off; off >>= 1) gp += __shfl_xor(gp, off, 64);

  if (lane == 0) {
    const float all_path = LN2 * (S + mx + LOG2F(sum));
    out[b] = all_path - gp;
  }
}

extern "C" void kernel_launch(void* const* d_in, const int* in_sizes, int n_in,
                              void* d_out, int out_size, void* d_ws, size_t ws_size,
                              hipStream_t stream) {
  const float* feats = (const float*)d_in[0];
  const float* trans = (const float*)d_in[1];
  const int*   tags  = (const int*)d_in[2];
  const int*   mask  = (const int*)d_in[3];
  float* out = (float*)d_out;

  const int B = out_size;  // 256
  crf_fwd_kernel<<<B, 64, 0, stream>>>(feats, trans, tags, mask, out);
}